// Round 11
// baseline (3080.573 us; speedup 1.0000x reference)
//
#include <hip/hip_runtime.h>
#include <hip/hip_fp16.h>
#include <hip/hip_cooperative_groups.h>

namespace cg = cooperative_groups;

#define NCH 21
#define NCH2 22         // 21 Q-channels + channel 21 = weight-sum (norm)
#define VSH 32          // value row stride in halves (64B line)
#define QSH 32          // Q row stride in halves (64B line)
#define USH 24          // -U row stride in halves (48B)
#define NPIX (512*512)  // 2^18
#define NTHR 256
#define DECODE12 (1.0f/(4095.f*128.f))
#define DECODE14 (1.0f/(16383.f*128.f))

// ---------------- wave-aggregated atomic rank ----------------
__device__ __forceinline__ int wave_rank_atomic(int m, bool valid, int* __restrict__ cur) {
  int lane = threadIdx.x & 63;
  unsigned long long todo = __ballot(valid);
  int out = 0;
  while (todo) {
    int leader = __ffsll((unsigned long long)todo) - 1;
    int lm = __shfl(m, leader);
    unsigned long long match = __ballot(valid && (m == lm));
    int cnt = __popcll(match);
    int b = 0;
    if (lane == leader) b = atomicAdd(&cur[lm], cnt);
    b = __shfl(b, leader);
    if (valid && (m == lm)) out = b + __popcll(match & ((1ull << lane) - 1ull));
    todo &= ~match;
  }
  return out;
}

// ---------------- build passes (slab order: t = j*NPIX + n) ----------------

__global__ void pack_count_kernel(const int* __restrict__ os_b, const float* __restrict__ ws_b,
                                  const int* __restrict__ os_s, const float* __restrict__ ws_s,
                                  unsigned int* __restrict__ sl, int* __restrict__ cnt,
                                  int nptot, int Mb) {
  int t = blockIdx.x*blockDim.x + threadIdx.x;
  bool valid = (t < nptot);
  int m = 0; float w = 0.f;
  if (valid) {
    if (t < 6*NPIX) { int j = t >> 18, n = t & (NPIX-1); m = os_b[n*6+j]; w = ws_b[n*6+j]; }
    else { int t2 = t - 6*NPIX; int j = t2 >> 18, n = t2 & (NPIX-1);
           m = Mb + os_s[n*3+j]; w = ws_s[n*3+j]; }
    int w12 = (int)(w * 4095.f + 0.5f);
    w12 = w12 < 0 ? 0 : (w12 > 4095 ? 4095 : w12);
    sl[t] = ((unsigned int)(m+1) << 12) | (unsigned int)w12;
  }
  int lane = threadIdx.x & 63;
  unsigned long long todo = __ballot(valid);
  while (todo) {
    int leader = __ffsll((unsigned long long)todo) - 1;
    int lm = __shfl(m, leader);
    unsigned long long match = __ballot(valid && (m == lm));
    if (lane == leader) atomicAdd(&cnt[lm], __popcll(match));
    todo &= ~match;
  }
}

__global__ void count_fused_kernel(const int* __restrict__ os_b, const int* __restrict__ os_s,
                                   int* __restrict__ cnt, int nptot, int Mb) {
  int t = blockIdx.x*blockDim.x + threadIdx.x;
  bool valid = (t < nptot);
  int m = 0;
  if (valid) {
    if (t < 6*NPIX) { int j = t >> 18, n = t & (NPIX-1); m = os_b[n*6+j]; }
    else { int t2 = t - 6*NPIX; int j = t2 >> 18, n = t2 & (NPIX-1); m = Mb + os_s[n*3+j]; }
  }
  int lane = threadIdx.x & 63;
  unsigned long long todo = __ballot(valid);
  while (todo) {
    int leader = __ffsll((unsigned long long)todo) - 1;
    int lm = __shfl(m, leader);
    unsigned long long match = __ballot(valid && (m == lm));
    if (lane == leader) atomicAdd(&cnt[lm], __popcll(match));
    todo &= ~match;
  }
}

__global__ void scan_block_kernel(const int* __restrict__ cnt, int* __restrict__ excl,
                                  int* __restrict__ bsum, int M) {
  __shared__ int s[256];
  int i = blockIdx.x*256 + threadIdx.x;
  int v = (i < M) ? cnt[i] : 0;
  s[threadIdx.x] = v;
  __syncthreads();
  for (int off = 1; off < 256; off <<= 1) {
    int t = (threadIdx.x >= off) ? s[threadIdx.x - off] : 0;
    __syncthreads();
    s[threadIdx.x] += t;
    __syncthreads();
  }
  if (i < M) excl[i] = s[threadIdx.x] - v;
  if (threadIdx.x == 255) bsum[blockIdx.x] = s[255];
}

__global__ void scan_sums_kernel(int* __restrict__ bsum, int nb) {
  __shared__ int s[256];
  __shared__ int carry;
  if (threadIdx.x == 0) carry = 0;
  __syncthreads();
  for (int base = 0; base < nb; base += 256) {
    int i = base + threadIdx.x;
    int v = (i < nb) ? bsum[i] : 0;
    s[threadIdx.x] = v;
    __syncthreads();
    for (int off = 1; off < 256; off <<= 1) {
      int t = (threadIdx.x >= off) ? s[threadIdx.x - off] : 0;
      __syncthreads();
      s[threadIdx.x] += t;
      __syncthreads();
    }
    if (i < nb) bsum[i] = s[threadIdx.x] - v + carry;
    int tot = s[255];
    __syncthreads();
    if (threadIdx.x == 0) carry += tot;
    __syncthreads();
  }
  if (threadIdx.x == 0) bsum[nb] = carry;
}

__global__ void scan_add_kernel(int* __restrict__ excl, const int* __restrict__ bsum,
                                int M, int nb) {
  int i = blockIdx.x*blockDim.x + threadIdx.x;
  if (i < M) excl[i] += bsum[i >> 8];
  else if (i == M) excl[M] = bsum[nb];
}

__global__ void fill_packed_kernel(const unsigned int* __restrict__ sl,
                                   const int* __restrict__ start, int* __restrict__ cur,
                                   unsigned int* __restrict__ pw, int nptot) {
  int t = blockIdx.x*blockDim.x + threadIdx.x;
  bool valid = (t < nptot);
  int m = 0; unsigned int e = 0;
  if (valid) {
    e = sl[t];
    m = (int)(e >> 12) - 1;
  }
  int slot = wave_rank_atomic(m, valid, cur);
  if (valid) {
    unsigned int pix = (unsigned int)(t & (NPIX-1));
    pw[start[m] + slot] = (pix << 12) | (e & 4095u);
  }
}

__global__ void fill_fused_kernel(const int* __restrict__ os_b, const float* __restrict__ ws_b,
                                  const int* __restrict__ os_s, const float* __restrict__ ws_s,
                                  const int* __restrict__ start, int* __restrict__ cur,
                                  unsigned int* __restrict__ pw, int nptot, int Mb) {
  int t = blockIdx.x*blockDim.x + threadIdx.x;
  bool valid = (t < nptot);
  int m = 0, pix = 0; float w = 0.f;
  if (valid) {
    if (t < 6*NPIX) { int j = t >> 18, n = t & (NPIX-1); m = os_b[n*6+j]; pix = n; w = ws_b[n*6+j]; }
    else { int t2 = t - 6*NPIX; int j = t2 >> 18, n = t2 & (NPIX-1);
           m = Mb + os_s[n*3+j]; pix = n; w = ws_s[n*3+j]; }
  }
  int slot = wave_rank_atomic(m, valid, cur);
  if (valid) {
    int w14 = (int)(w * 16383.f + 0.5f);
    w14 = w14 < 0 ? 0 : (w14 > 16383 ? 16383 : w14);
    pw[start[m] + slot] = ((unsigned int)pix << 14) | (unsigned int)w14;
  }
}

// ---------------- cooperative mega-kernel (grid-stride all phases) ----------------

struct MegaParams {
  const float* U;
  __half* Qh;
  __half* Uh;
  const int* start;
  const unsigned int* pw;
  const unsigned int* sl;
  __half* vAb; __half* vBb; __half* vAs; __half* vBs;
  const int* bn_b; const int* bn_s;
  float* out;
  int Mb, Ms, Mtot;
};

__global__ void __launch_bounds__(NTHR, 4) crf_mega_kernel(MegaParams p) {
  cg::grid_group grid = cg::this_grid();
  const int total = (int)gridDim.x * NTHR;
  const int tid = blockIdx.x*NTHR + threadIdx.x;
  const int lane = threadIdx.x & 63;
  const int wave = tid >> 6;
  const int nwaves = total >> 6;

  // ---- init: Uh = -U (fp16), Qh = softmax(-U) (fp16) ----
  for (int n = tid; n < NPIX; n += total) {
    float l[NCH]; float mx = -3.4e38f;
    #pragma unroll
    for (int c = 0; c < NCH; ++c) {
      l[c] = -p.U[(size_t)n*NCH + c];
      p.Uh[(size_t)n*USH + c] = __float2half(l[c]);
      mx = fmaxf(mx, l[c]);
    }
    float s = 0.f;
    #pragma unroll
    for (int c = 0; c < NCH; ++c) { l[c] = expf(l[c]-mx); s += l[c]; }
    float r = 1.0f/s;
    #pragma unroll
    for (int c = 0; c < NCH; ++c) p.Qh[(size_t)n*QSH + c] = __float2half(l[c]*r);
    p.Qh[(size_t)n*QSH + NCH] = __float2half(0.f);   // ch21 read by half2 gather
  }
  grid.sync();

  const int pg = lane/11;              // 0..5 (pg==5 -> lanes 55..63 idle)
  const int c2 = lane - pg*11;         // half2 chunk 0..10 (channels 2c2, 2c2+1)

  for (int it = 0; it < 5; ++it) {
    // ---- gather splat: wave per lattice point, 5 pair-groups x 11 half2-channels ----
    for (int wid = wave; wid < p.Mtot; wid += nwaves) {
      int k0 = p.start[wid], k1 = p.start[wid+1];
      float ax = 0.f, ay = 0.f, wsum = 0.f;
      if (pg < 5) {
        int k = k0 + pg;
        for (; k + 5 < k1; k += 10) {
          unsigned int e0 = p.pw[k], e1 = p.pw[k+5];
          float w0 = (float)(e0 & 4095u), w1 = (float)(e1 & 4095u);
          float2 f0 = __half22float2(*(const __half2*)(p.Qh + ((size_t)(e0 >> 12) << 5) + 2*c2));
          float2 f1 = __half22float2(*(const __half2*)(p.Qh + ((size_t)(e1 >> 12) << 5) + 2*c2));
          ax += w0*f0.x + w1*f1.x;
          ay += w0*f0.y + w1*f1.y;
          wsum += w0 + w1;
        }
        if (k < k1) {
          unsigned int e0 = p.pw[k];
          float w0 = (float)(e0 & 4095u);
          float2 f0 = __half22float2(*(const __half2*)(p.Qh + ((size_t)(e0 >> 12) << 5) + 2*c2));
          ax += w0*f0.x; ay += w0*f0.y; wsum += w0;
        }
      }
      float sx = ax, sy = ay, wt = wsum;
      #pragma unroll
      for (int g = 1; g < 5; ++g) {
        sx += __shfl(ax, lane + 11*g);
        sy += __shfl(ay, lane + 11*g);
        wt += __shfl(wsum, lane + 11*g);
      }
      if (lane < 11) {
        __half* row = (wid < p.Mb) ? (p.vAb + (size_t)(wid+1)*VSH)
                                   : (p.vAs + (size_t)(wid-p.Mb+1)*VSH);
        float hy = (lane == 10) ? wt : sy;     // value ch21 = weight sum (norm)
        *(__half2*)(row + 2*lane) = __floats2half2_rn(sx*DECODE12, hy*DECODE12);
      }
    }
    grid.sync();

    // ---- 6 Jacobi blur steps (bilateral all 6, spatial first 3) ----
    __half *ab = p.vAb, *bb = p.vBb, *as = p.vAs, *bs = p.vBs;
    for (int j = 0; j < 6; ++j) {
      int ms = (j < 3) ? p.Ms : 0;
      int tb = p.Mb*11, tot = tb + ms*11;
      const int* bnb = p.bn_b + (size_t)j*p.Mb*2;
      const int* bns = p.bn_s + (size_t)j*p.Ms*2;
      for (int t = tid; t < tot; t += total) {
        const __half* in; __half* out; const int* bn; int i, jj;
        if (t < tb) { i = t/11; jj = t - i*11; in = ab; out = bb; bn = bnb; }
        else { int t2 = t - tb; i = t2/11; jj = t2 - i*11; in = as; out = bs; bn = bns; }
        int b0 = bn[2*i], b1 = bn[2*i+1];
        float2 a = __half22float2(((const __half2*)(in + (size_t)(i+1)*VSH))[jj]);
        float2 x = __half22float2(((const __half2*)(in + (size_t)b0*VSH))[jj]);
        float2 y = __half22float2(((const __half2*)(in + (size_t)b1*VSH))[jj]);
        float2 o;
        o.x = a.x + 0.5f*(x.x + y.x);
        o.y = a.y + 0.5f*(x.y + y.y);
        ((__half2*)(out + (size_t)(i+1)*VSH))[jj] = __float22half2_rn(o);
      }
      grid.sync();
      { __half* tp = ab; ab = bb; bb = tp; }
      if (j < 3) { __half* tp = as; as = bs; bs = tp; }
    }
    // ab == vAb (6 swaps), as == vBs (3 swaps)

    // ---- slice both lattices + combine + softmax ----
    {
      const __half* vb = ab;
      const __half* vsShift = as - (size_t)p.Mb*VSH;   // unified-m indexing
      for (int n = tid; n < NPIX; n += total) {
        float l[NCH];
        #pragma unroll
        for (int c = 0; c < NCH; ++c) l[c] = __half2float(p.Uh[(size_t)n*USH + c]);
        float acc[NCH2];
        #pragma unroll
        for (int c = 0; c < NCH2; ++c) acc[c] = 0.f;
        #pragma unroll
        for (int j = 0; j < 6; ++j) {
          unsigned int e = p.sl[(size_t)j*NPIX + n];
          float w = (float)(e & 4095u);
          const __half* v = vb + ((size_t)(e >> 12) << 5);
          #pragma unroll
          for (int c = 0; c < NCH2; ++c) acc[c] += w*__half2float(v[c]);
        }
        float rb = 10.0f/(acc[NCH] + 1e-12f);
        #pragma unroll
        for (int c = 0; c < NCH; ++c) l[c] += rb*acc[c];
        #pragma unroll
        for (int c = 0; c < NCH2; ++c) acc[c] = 0.f;
        #pragma unroll
        for (int j = 0; j < 3; ++j) {
          unsigned int e = p.sl[(size_t)(6+j)*NPIX + n];
          float w = (float)(e & 4095u);
          const __half* v = vsShift + ((size_t)(e >> 12) << 5);
          #pragma unroll
          for (int c = 0; c < NCH2; ++c) acc[c] += w*__half2float(v[c]);
        }
        float rs = 3.0f/(acc[NCH] + 1e-12f);
        #pragma unroll
        for (int c = 0; c < NCH; ++c) l[c] += rs*acc[c];
        float mx = -3.4e38f;
        #pragma unroll
        for (int c = 0; c < NCH; ++c) mx = fmaxf(mx, l[c]);
        float s = 0.f;
        #pragma unroll
        for (int c = 0; c < NCH; ++c) { l[c] = expf(l[c]-mx); s += l[c]; }
        float r = 1.0f/s;
        if (it == 4) {
          #pragma unroll
          for (int c = 0; c < NCH; ++c) p.out[(size_t)n*NCH + c] = l[c]*r;
        } else {
          #pragma unroll
          for (int c = 0; c < NCH; ++c) p.Qh[(size_t)n*QSH + c] = __float2half(l[c]*r);
          p.Qh[(size_t)n*QSH + NCH] = __float2half(0.f);
        }
      }
    }
    grid.sync();
  }
}

// ---------------- fallback iteration kernels (round-9 proven) ----------------

template<int WBITS>
__global__ void gather_wave_kernel(const __half* __restrict__ Qh, const int* __restrict__ start,
                                   const unsigned int* __restrict__ pw,
                                   __half* __restrict__ valsB, __half* __restrict__ valsS,
                                   int Mb, int Mtot, float decode) {
  const unsigned int WMASK = (1u << WBITS) - 1u;
  int wid = blockIdx.x*(blockDim.x >> 6) + (threadIdx.x >> 6);
  if (wid >= Mtot) return;
  int lane = threadIdx.x & 63;
  int pg = lane / 21;
  int c  = lane - pg*21;
  float s = 0.f, wsum = 0.f;
  int k1 = start[wid+1];
  if (pg < 3) {
    int k = start[wid] + pg;
    for (; k + 9 < k1; k += 12) {
      unsigned int a0 = pw[k], a1 = pw[k+3], a2 = pw[k+6], a3 = pw[k+9];
      float w0 = (float)(a0 & WMASK), w1 = (float)(a1 & WMASK);
      float w2 = (float)(a2 & WMASK), w3 = (float)(a3 & WMASK);
      s += w0 * __half2float(Qh[((size_t)(a0 >> WBITS) << 5) + c])
         + w1 * __half2float(Qh[((size_t)(a1 >> WBITS) << 5) + c])
         + w2 * __half2float(Qh[((size_t)(a2 >> WBITS) << 5) + c])
         + w3 * __half2float(Qh[((size_t)(a3 >> WBITS) << 5) + c]);
      wsum += w0 + w1 + w2 + w3;
    }
    for (; k < k1; k += 3) {
      unsigned int a = pw[k];
      float w = (float)(a & WMASK);
      s += w * __half2float(Qh[((size_t)(a >> WBITS) << 5) + c]);
      wsum += w;
    }
  }
  float s1 = __shfl(s, (lane + 21) & 63);
  float s2 = __shfl(s, (lane + 42) & 63);
  float wt = __shfl(wsum, 0) + __shfl(wsum, 21) + __shfl(wsum, 42);
  __half* row = (wid < Mb) ? (valsB + (size_t)(wid+1)*VSH)
                           : (valsS + (size_t)(wid-Mb+1)*VSH);
  if (lane < 21)       row[c]  = __float2half((s + s1 + s2) * decode);
  else if (lane == 21) row[21] = __float2half(wt * decode);
}

__global__ void blurH_fused_kernel(const __half* __restrict__ inB, __half* __restrict__ outB,
                                   const int* __restrict__ bnB, int Mb,
                                   const __half* __restrict__ inS, __half* __restrict__ outS,
                                   const int* __restrict__ bnS, int Ms) {
  int t = blockIdx.x*blockDim.x + threadIdx.x;
  const __half* in; __half* out; const int* bn; int i, j;
  int tb = Mb*11;
  if (t < tb) { i = t/11; j = t - i*11; in = inB; out = outB; bn = bnB; }
  else {
    int t2 = t - tb;
    if (t2 >= Ms*11) return;
    i = t2/11; j = t2 - i*11; in = inS; out = outS; bn = bnS;
  }
  int b0 = bn[2*i], b1 = bn[2*i+1];
  float2 a = __half22float2(((const __half2*)(in + (size_t)(i+1)*VSH))[j]);
  float2 x = __half22float2(((const __half2*)(in + (size_t)b0*VSH))[j]);
  float2 y = __half22float2(((const __half2*)(in + (size_t)b1*VSH))[j]);
  float2 o;
  o.x = a.x + 0.5f*(x.x + y.x);
  o.y = a.y + 0.5f*(x.y + y.y);
  ((__half2*)(out + (size_t)(i+1)*VSH))[j] = __float22half2_rn(o);
}

__global__ void softmax_init_kernel(const float* __restrict__ U, __half* __restrict__ Qh,
                                    __half* __restrict__ Uh) {
  int n = blockIdx.x*blockDim.x + threadIdx.x;
  if (n >= NPIX) return;
  float l[NCH];
  float m = -3.4e38f;
  #pragma unroll
  for (int c = 0; c < NCH; ++c) {
    l[c] = -U[(size_t)n*NCH+c];
    Uh[(size_t)n*USH+c] = __float2half(l[c]);
    m = fmaxf(m, l[c]);
  }
  float s = 0.f;
  #pragma unroll
  for (int c = 0; c < NCH; ++c) { l[c] = expf(l[c]-m); s += l[c]; }
  float r = 1.0f/s;
  #pragma unroll
  for (int c = 0; c < NCH; ++c) Qh[(size_t)n*QSH+c] = __float2half(l[c]*r);
  Qh[(size_t)n*QSH+NCH] = __float2half(0.f);
}

template<bool FINAL, bool PACKED>
__global__ void slice_combine_softmax_kernel(
    const __half* __restrict__ Uh,
    const __half* __restrict__ vb, const __half* __restrict__ vsShift,
    const unsigned int* __restrict__ sl,
    const float* __restrict__ ws_b, const int* __restrict__ os_b,
    const float* __restrict__ ws_s, const int* __restrict__ os_s,
    float* __restrict__ QoutF, __half* __restrict__ QoutH) {
  int n = blockIdx.x*blockDim.x + threadIdx.x;
  if (n >= NPIX) return;
  float l[NCH];
  #pragma unroll
  for (int c = 0; c < NCH; ++c) l[c] = __half2float(Uh[(size_t)n*USH+c]);
  float acc[NCH2];
  #pragma unroll
  for (int c = 0; c < NCH2; ++c) acc[c] = 0.f;
  #pragma unroll
  for (int j = 0; j < 6; ++j) {
    float w; const __half* v;
    if (PACKED) {
      unsigned int e = sl[(size_t)j*NPIX + n];
      w = (float)(e & 4095u);
      v = vb + ((size_t)(e >> 12) << 5);
    } else {
      w = ws_b[n*6+j];
      v = vb + (size_t)(os_b[n*6+j]+1)*VSH;
    }
    #pragma unroll
    for (int c = 0; c < NCH2; ++c) acc[c] += w*__half2float(v[c]);
  }
  float rb = 10.0f/(acc[NCH] + 1e-12f);
  #pragma unroll
  for (int c = 0; c < NCH; ++c) l[c] += rb*acc[c];
  #pragma unroll
  for (int c = 0; c < NCH2; ++c) acc[c] = 0.f;
  #pragma unroll
  for (int j = 0; j < 3; ++j) {
    float w; const __half* v;
    if (PACKED) {
      unsigned int e = sl[(size_t)(6+j)*NPIX + n];
      w = (float)(e & 4095u);
      v = vsShift + ((size_t)(e >> 12) << 5);
    } else {
      w = ws_s[n*3+j];
      v = vsShift + (size_t)(os_s[n*3+j]+1)*VSH;
    }
    #pragma unroll
    for (int c = 0; c < NCH2; ++c) acc[c] += w*__half2float(v[c]);
  }
  float rs = 3.0f/(acc[NCH] + 1e-12f);
  #pragma unroll
  for (int c = 0; c < NCH; ++c) l[c] += rs*acc[c];
  float m = -3.4e38f;
  #pragma unroll
  for (int c = 0; c < NCH; ++c) m = fmaxf(m, l[c]);
  float s = 0.f;
  #pragma unroll
  for (int c = 0; c < NCH; ++c) { l[c] = expf(l[c]-m); s += l[c]; }
  float r = 1.0f/s;
  if (FINAL) {
    #pragma unroll
    for (int c = 0; c < NCH; ++c) QoutF[(size_t)n*NCH+c] = l[c]*r;
  } else {
    #pragma unroll
    for (int c = 0; c < NCH; ++c) QoutH[(size_t)n*QSH+c] = __float2half(l[c]*r);
    QoutH[(size_t)n*QSH+NCH] = __float2half(0.f);
  }
}

// ---------------- host ----------------

extern "C" void kernel_launch(void* const* d_in, const int* in_sizes, int n_in,
                              void* d_out, int out_size, void* d_ws, size_t ws_size,
                              hipStream_t stream) {
  const float* U    = (const float*)d_in[0];
  const float* ws_b = (const float*)d_in[1];
  const float* ws_s = (const float*)d_in[2];
  const int*   os_b = (const int*)d_in[3];
  const int*   os_s = (const int*)d_in[4];
  const int*   bn_b = (const int*)d_in[5];
  const int*   bn_s = (const int*)d_in[6];
  const int Mb = in_sizes[5] / 12;
  const int Ms = in_sizes[6] / 6;
  const int Mtot = Mb + Ms;
  const int nptot = NPIX*9;
  const bool packed = (Mtot + 1) < (1 << 20);

  char* wcur = (char*)d_ws;
  auto alloc = [&](size_t bytes) -> void* {
    void* p = (void*)wcur;
    wcur += (bytes + 63) & ~(size_t)63;
    return p;
  };
  __half* Qh     = (__half*)alloc((size_t)NPIX*QSH*2);
  __half* Uh     = (__half*)alloc((size_t)NPIX*USH*2);
  __half* vAb    = (__half*)alloc((size_t)(Mb+1)*VSH*2);
  __half* vBb    = (__half*)alloc((size_t)(Mb+1)*VSH*2);
  __half* vAs    = (__half*)alloc((size_t)(Ms+1)*VSH*2);
  __half* vBs    = (__half*)alloc((size_t)(Ms+1)*VSH*2);
  int*   start   = (int*)alloc((size_t)(Mtot+1)*4);
  int*   cur     = (int*)alloc((size_t)Mtot*4);
  unsigned int* pw = (unsigned int*)alloc((size_t)nptot*4);
  unsigned int* sl = (unsigned int*)alloc((size_t)nptot*4);
  int*   bsum    = (int*)alloc((size_t)(Mtot/256 + 3)*4);

  const int TB = 256;
  auto blocks = [](long long n){ return (int)((n + 255)/256); };
  const int nbM = blocks(Mtot);

  // ---- build: pack+count (one pass), scan, fill ----
  hipMemsetAsync(cur, 0, (size_t)Mtot*sizeof(int), stream);
  if (packed)
    pack_count_kernel<<<blocks(nptot), TB, 0, stream>>>(os_b, ws_b, os_s, ws_s,
                                                        sl, cur, nptot, Mb);
  else
    count_fused_kernel<<<blocks(nptot), TB, 0, stream>>>(os_b, os_s, cur, nptot, Mb);
  scan_block_kernel<<<nbM, 256, 0, stream>>>(cur, start, bsum, Mtot);
  scan_sums_kernel<<<1, 256, 0, stream>>>(bsum, nbM);
  scan_add_kernel<<<blocks(Mtot+1), TB, 0, stream>>>(start, bsum, Mtot, nbM);
  hipMemsetAsync(cur, 0, (size_t)Mtot*sizeof(int), stream);
  if (packed)
    fill_packed_kernel<<<blocks(nptot), TB, 0, stream>>>(sl, start, cur, pw, nptot);
  else
    fill_fused_kernel<<<blocks(nptot), TB, 0, stream>>>(os_b, ws_b, os_s, ws_s,
                                                        start, cur, pw, nptot, Mb);

  // ---- zero sentinel row 0 of value buffers ----
  hipMemsetAsync(vAb, 0, VSH*2, stream);
  hipMemsetAsync(vBb, 0, VSH*2, stream);
  hipMemsetAsync(vAs, 0, VSH*2, stream);
  hipMemsetAsync(vBs, 0, VSH*2, stream);

  bool coop_done = false;
  if (packed) {
    // size cooperative grid from occupancy (launch rejects non-co-resident grids)
    int occ = 0, numCU = 0, dev = 0;
    hipGetDevice(&dev);
    hipDeviceGetAttribute(&numCU, hipDeviceAttributeMultiprocessorCount, dev);
    hipError_t oe = hipOccupancyMaxActiveBlocksPerMultiprocessor(&occ, crf_mega_kernel, NTHR, 0);
    int nblk = (oe == hipSuccess) ? occ * numCU : 0;
    if (nblk > 1024) nblk = 1024;
    if (nblk > 0) {
      MegaParams p;
      p.U = U; p.Qh = Qh; p.Uh = Uh;
      p.start = start; p.pw = pw; p.sl = sl;
      p.vAb = vAb; p.vBb = vBb; p.vAs = vAs; p.vBs = vBs;
      p.bn_b = bn_b; p.bn_s = bn_s;
      p.out = (float*)d_out;
      p.Mb = Mb; p.Ms = Ms; p.Mtot = Mtot;
      void* kargs[] = { &p };
      hipError_t lerr = hipLaunchCooperativeKernel((const void*)crf_mega_kernel,
                                                   dim3(nblk), dim3(NTHR), kargs, 0, stream);
      coop_done = (lerr == hipSuccess);
    }
  }

  if (!coop_done) {
    // fallback: round-9 separate-kernel pipeline (proven)
    softmax_init_kernel<<<blocks(NPIX), TB, 0, stream>>>(U, Qh, Uh);
    for (int it = 0; it < 5; ++it) {
      if (packed)
        gather_wave_kernel<12><<<blocks((long long)Mtot*64), TB, 0, stream>>>(
            Qh, start, pw, vAb, vAs, Mb, Mtot, DECODE12);
      else
        gather_wave_kernel<14><<<blocks((long long)Mtot*64), TB, 0, stream>>>(
            Qh, start, pw, vAb, vAs, Mb, Mtot, DECODE14);
      __half* ab = vAb; __half* bb = vBb;
      __half* as = vAs; __half* bs = vBs;
      for (int j = 0; j < 6; ++j) {
        int ms = (j < 3) ? Ms : 0;
        blurH_fused_kernel<<<blocks((long long)(Mb + ms)*11), TB, 0, stream>>>(
            ab, bb, bn_b + (size_t)j*Mb*2, Mb, as, bs, bn_s + (size_t)j*Ms*2, ms);
        { __half* t = ab; ab = bb; bb = t; }
        if (j < 3) { __half* t = as; as = bs; bs = t; }
      }
      const __half* vsArg = packed ? (as - (size_t)Mb*VSH) : as;
      if (it == 4) {
        if (packed)
          slice_combine_softmax_kernel<true,true><<<blocks(NPIX), TB, 0, stream>>>(
              Uh, ab, vsArg, sl, ws_b, os_b, ws_s, os_s, (float*)d_out, (__half*)nullptr);
        else
          slice_combine_softmax_kernel<true,false><<<blocks(NPIX), TB, 0, stream>>>(
              Uh, ab, vsArg, sl, ws_b, os_b, ws_s, os_s, (float*)d_out, (__half*)nullptr);
      } else {
        if (packed)
          slice_combine_softmax_kernel<false,true><<<blocks(NPIX), TB, 0, stream>>>(
              Uh, ab, vsArg, sl, ws_b, os_b, ws_s, os_s, (float*)nullptr, Qh);
        else
          slice_combine_softmax_kernel<false,false><<<blocks(NPIX), TB, 0, stream>>>(
              Uh, ab, vsArg, sl, ws_b, os_b, ws_s, os_s, (float*)nullptr, Qh);
      }
    }
  }
}

// Round 12
// 482.601 us; speedup vs baseline: 6.3833x; 6.3833x over previous
//
#include <hip/hip_runtime.h>
#include <hip/hip_fp16.h>

#define NCH 21
#define NCH2 22         // 21 Q-channels + channel 21 = weight-sum (norm)
#define VSH 32          // value row stride in halves (64B line)
#define QSH 32          // Q row stride in halves (64B line)
#define USH 24          // -U row stride in halves (48B)
#define NPIX (512*512)  // 2^18
#define DECODE12 (1.0f/(4095.f*128.f))
#define DECODE14 (1.0f/(16383.f*128.f))

// ---------------- wave-aggregated atomic rank ----------------
__device__ __forceinline__ int wave_rank_atomic(int m, bool valid, int* __restrict__ cur) {
  int lane = threadIdx.x & 63;
  unsigned long long todo = __ballot(valid);
  int out = 0;
  while (todo) {
    int leader = __ffsll((unsigned long long)todo) - 1;
    int lm = __shfl(m, leader);
    unsigned long long match = __ballot(valid && (m == lm));
    int cnt = __popcll(match);
    int b = 0;
    if (lane == leader) b = atomicAdd(&cur[lm], cnt);
    b = __shfl(b, leader);
    if (valid && (m == lm)) out = b + __popcll(match & ((1ull << lane) - 1ull));
    todo &= ~match;
  }
  return out;
}

// ---------------- build passes (slab order: t = j*NPIX + n) ----------------

__global__ void pack_count_kernel(const int* __restrict__ os_b, const float* __restrict__ ws_b,
                                  const int* __restrict__ os_s, const float* __restrict__ ws_s,
                                  unsigned int* __restrict__ sl, int* __restrict__ cnt,
                                  int nptot, int Mb) {
  int t = blockIdx.x*blockDim.x + threadIdx.x;
  bool valid = (t < nptot);
  int m = 0; float w = 0.f;
  if (valid) {
    if (t < 6*NPIX) { int j = t >> 18, n = t & (NPIX-1); m = os_b[n*6+j]; w = ws_b[n*6+j]; }
    else { int t2 = t - 6*NPIX; int j = t2 >> 18, n = t2 & (NPIX-1);
           m = Mb + os_s[n*3+j]; w = ws_s[n*3+j]; }
    int w12 = (int)(w * 4095.f + 0.5f);
    w12 = w12 < 0 ? 0 : (w12 > 4095 ? 4095 : w12);
    sl[t] = ((unsigned int)(m+1) << 12) | (unsigned int)w12;
  }
  int lane = threadIdx.x & 63;
  unsigned long long todo = __ballot(valid);
  while (todo) {
    int leader = __ffsll((unsigned long long)todo) - 1;
    int lm = __shfl(m, leader);
    unsigned long long match = __ballot(valid && (m == lm));
    if (lane == leader) atomicAdd(&cnt[lm], __popcll(match));
    todo &= ~match;
  }
}

__global__ void count_fused_kernel(const int* __restrict__ os_b, const int* __restrict__ os_s,
                                   int* __restrict__ cnt, int nptot, int Mb) {
  int t = blockIdx.x*blockDim.x + threadIdx.x;
  bool valid = (t < nptot);
  int m = 0;
  if (valid) {
    if (t < 6*NPIX) { int j = t >> 18, n = t & (NPIX-1); m = os_b[n*6+j]; }
    else { int t2 = t - 6*NPIX; int j = t2 >> 18, n = t2 & (NPIX-1); m = Mb + os_s[n*3+j]; }
  }
  int lane = threadIdx.x & 63;
  unsigned long long todo = __ballot(valid);
  while (todo) {
    int leader = __ffsll((unsigned long long)todo) - 1;
    int lm = __shfl(m, leader);
    unsigned long long match = __ballot(valid && (m == lm));
    if (lane == leader) atomicAdd(&cnt[lm], __popcll(match));
    todo &= ~match;
  }
}

__global__ void scan_block_kernel(const int* __restrict__ cnt, int* __restrict__ excl,
                                  int* __restrict__ bsum, int M) {
  __shared__ int s[256];
  int i = blockIdx.x*256 + threadIdx.x;
  int v = (i < M) ? cnt[i] : 0;
  s[threadIdx.x] = v;
  __syncthreads();
  for (int off = 1; off < 256; off <<= 1) {
    int t = (threadIdx.x >= off) ? s[threadIdx.x - off] : 0;
    __syncthreads();
    s[threadIdx.x] += t;
    __syncthreads();
  }
  if (i < M) excl[i] = s[threadIdx.x] - v;
  if (threadIdx.x == 255) bsum[blockIdx.x] = s[255];
}

__global__ void scan_sums_kernel(int* __restrict__ bsum, int nb) {
  __shared__ int s[256];
  __shared__ int carry;
  if (threadIdx.x == 0) carry = 0;
  __syncthreads();
  for (int base = 0; base < nb; base += 256) {
    int i = base + threadIdx.x;
    int v = (i < nb) ? bsum[i] : 0;
    s[threadIdx.x] = v;
    __syncthreads();
    for (int off = 1; off < 256; off <<= 1) {
      int t = (threadIdx.x >= off) ? s[threadIdx.x - off] : 0;
      __syncthreads();
      s[threadIdx.x] += t;
      __syncthreads();
    }
    if (i < nb) bsum[i] = s[threadIdx.x] - v + carry;
    int tot = s[255];
    __syncthreads();
    if (threadIdx.x == 0) carry += tot;
    __syncthreads();
  }
  if (threadIdx.x == 0) bsum[nb] = carry;
}

__global__ void scan_add_kernel(int* __restrict__ excl, const int* __restrict__ bsum,
                                int M, int nb) {
  int i = blockIdx.x*blockDim.x + threadIdx.x;
  if (i < M) excl[i] += bsum[i >> 8];
  else if (i == M) excl[M] = bsum[nb];
}

__global__ void fill_packed_kernel(const unsigned int* __restrict__ sl,
                                   const int* __restrict__ start, int* __restrict__ cur,
                                   unsigned int* __restrict__ pw, int nptot) {
  int t = blockIdx.x*blockDim.x + threadIdx.x;
  bool valid = (t < nptot);
  int m = 0; unsigned int e = 0;
  if (valid) {
    e = sl[t];
    m = (int)(e >> 12) - 1;
  }
  int slot = wave_rank_atomic(m, valid, cur);
  if (valid) {
    unsigned int pix = (unsigned int)(t & (NPIX-1));
    pw[start[m] + slot] = (pix << 12) | (e & 4095u);
  }
}

__global__ void fill_fused_kernel(const int* __restrict__ os_b, const float* __restrict__ ws_b,
                                  const int* __restrict__ os_s, const float* __restrict__ ws_s,
                                  const int* __restrict__ start, int* __restrict__ cur,
                                  unsigned int* __restrict__ pw, int nptot, int Mb) {
  int t = blockIdx.x*blockDim.x + threadIdx.x;
  bool valid = (t < nptot);
  int m = 0, pix = 0; float w = 0.f;
  if (valid) {
    if (t < 6*NPIX) { int j = t >> 18, n = t & (NPIX-1); m = os_b[n*6+j]; pix = n; w = ws_b[n*6+j]; }
    else { int t2 = t - 6*NPIX; int j = t2 >> 18, n = t2 & (NPIX-1);
           m = Mb + os_s[n*3+j]; pix = n; w = ws_s[n*3+j]; }
  }
  int slot = wave_rank_atomic(m, valid, cur);
  if (valid) {
    int w14 = (int)(w * 16383.f + 0.5f);
    w14 = w14 < 0 ? 0 : (w14 > 16383 ? 16383 : w14);
    pw[start[m] + slot] = ((unsigned int)pix << 14) | (unsigned int)w14;
  }
}

// ---------------- lattice ops ----------------

// packed gather splat, wave-per-lattice-point: 5 pair-groups x 11 half2 chunks,
// 2-deep unroll -> 10 Q-line loads in flight per wave. ch21 of value row = weight
// sum (norm); ch21 of Qh is kept zero so the chunk-10 half2 read is harmless.
// (layout validated end-to-end by the round-11 mega kernel run)
__global__ void gather_half2_kernel(const __half* __restrict__ Qh, const int* __restrict__ start,
                                    const unsigned int* __restrict__ pw,
                                    __half* __restrict__ valsB, __half* __restrict__ valsS,
                                    int Mb, int Mtot) {
  int wid = blockIdx.x*(blockDim.x >> 6) + (threadIdx.x >> 6);
  if (wid >= Mtot) return;
  int lane = threadIdx.x & 63;
  int pg = lane/11;                    // 0..5 (pg==5 -> lanes 55..63 idle)
  int c2 = lane - pg*11;               // half2 chunk 0..10
  int k0 = start[wid], k1 = start[wid+1];
  float ax = 0.f, ay = 0.f, wsum = 0.f;
  if (pg < 5) {
    int k = k0 + pg;
    for (; k + 5 < k1; k += 10) {
      unsigned int e0 = pw[k], e1 = pw[k+5];
      float w0 = (float)(e0 & 4095u), w1 = (float)(e1 & 4095u);
      float2 f0 = __half22float2(*(const __half2*)(Qh + ((size_t)(e0 >> 12) << 5) + 2*c2));
      float2 f1 = __half22float2(*(const __half2*)(Qh + ((size_t)(e1 >> 12) << 5) + 2*c2));
      ax += w0*f0.x + w1*f1.x;
      ay += w0*f0.y + w1*f1.y;
      wsum += w0 + w1;
    }
    if (k < k1) {
      unsigned int e0 = pw[k];
      float w0 = (float)(e0 & 4095u);
      float2 f0 = __half22float2(*(const __half2*)(Qh + ((size_t)(e0 >> 12) << 5) + 2*c2));
      ax += w0*f0.x; ay += w0*f0.y; wsum += w0;
    }
  }
  float sx = ax, sy = ay, wt = wsum;
  #pragma unroll
  for (int g = 1; g < 5; ++g) {
    sx += __shfl(ax, lane + 11*g);
    sy += __shfl(ay, lane + 11*g);
    wt += __shfl(wsum, lane + 11*g);
  }
  if (lane < 11) {
    __half* row = (wid < Mb) ? (valsB + (size_t)(wid+1)*VSH)
                             : (valsS + (size_t)(wid-Mb+1)*VSH);
    float hy = (lane == 10) ? wt : sy;   // value ch21 = weight sum (norm)
    *(__half2*)(row + 2*lane) = __floats2half2_rn(sx*DECODE12, hy*DECODE12);
  }
}

// fallback gather (14-bit pw), 3x21 scalar layout
__global__ void gather_wave_kernel(const __half* __restrict__ Qh, const int* __restrict__ start,
                                   const unsigned int* __restrict__ pw,
                                   __half* __restrict__ valsB, __half* __restrict__ valsS,
                                   int Mb, int Mtot) {
  const unsigned int WMASK = (1u << 14) - 1u;
  int wid = blockIdx.x*(blockDim.x >> 6) + (threadIdx.x >> 6);
  if (wid >= Mtot) return;
  int lane = threadIdx.x & 63;
  int pg = lane / 21;
  int c  = lane - pg*21;
  float s = 0.f, wsum = 0.f;
  int k1 = start[wid+1];
  if (pg < 3) {
    int k = start[wid] + pg;
    for (; k + 9 < k1; k += 12) {
      unsigned int a0 = pw[k], a1 = pw[k+3], a2 = pw[k+6], a3 = pw[k+9];
      float w0 = (float)(a0 & WMASK), w1 = (float)(a1 & WMASK);
      float w2 = (float)(a2 & WMASK), w3 = (float)(a3 & WMASK);
      s += w0 * __half2float(Qh[((size_t)(a0 >> 14) << 5) + c])
         + w1 * __half2float(Qh[((size_t)(a1 >> 14) << 5) + c])
         + w2 * __half2float(Qh[((size_t)(a2 >> 14) << 5) + c])
         + w3 * __half2float(Qh[((size_t)(a3 >> 14) << 5) + c]);
      wsum += w0 + w1 + w2 + w3;
    }
    for (; k < k1; k += 3) {
      unsigned int a = pw[k];
      float w = (float)(a & WMASK);
      s += w * __half2float(Qh[((size_t)(a >> 14) << 5) + c]);
      wsum += w;
    }
  }
  float s1 = __shfl(s, (lane + 21) & 63);
  float s2 = __shfl(s, (lane + 42) & 63);
  float wt = __shfl(wsum, 0) + __shfl(wsum, 21) + __shfl(wsum, 42);
  __half* row = (wid < Mb) ? (valsB + (size_t)(wid+1)*VSH)
                           : (valsS + (size_t)(wid-Mb+1)*VSH);
  if (lane < 21)       row[c]  = __float2half((s + s1 + s2) * DECODE14);
  else if (lane == 21) row[21] = __float2half(wt * DECODE14);
}

// blur on fp16 rows, half2 chunks (11 chunks = 22 channels), fp32 math
__global__ void blurH_fused_kernel(const __half* __restrict__ inB, __half* __restrict__ outB,
                                   const int* __restrict__ bnB, int Mb,
                                   const __half* __restrict__ inS, __half* __restrict__ outS,
                                   const int* __restrict__ bnS, int Ms) {
  int t = blockIdx.x*blockDim.x + threadIdx.x;
  const __half* in; __half* out; const int* bn; int i, j;
  int tb = Mb*11;
  if (t < tb) { i = t/11; j = t - i*11; in = inB; out = outB; bn = bnB; }
  else {
    int t2 = t - tb;
    if (t2 >= Ms*11) return;
    i = t2/11; j = t2 - i*11; in = inS; out = outS; bn = bnS;
  }
  int b0 = bn[2*i], b1 = bn[2*i+1];
  float2 a = __half22float2(((const __half2*)(in + (size_t)(i+1)*VSH))[j]);
  float2 x = __half22float2(((const __half2*)(in + (size_t)b0*VSH))[j]);
  float2 y = __half22float2(((const __half2*)(in + (size_t)b1*VSH))[j]);
  float2 o;
  o.x = a.x + 0.5f*(x.x + y.x);
  o.y = a.y + 0.5f*(x.y + y.y);
  ((__half2*)(out + (size_t)(i+1)*VSH))[j] = __float22half2_rn(o);
}

// ---------------- pixel-side kernels ----------------

__global__ void softmax_init_kernel(const float* __restrict__ U, __half* __restrict__ Qh,
                                    __half* __restrict__ Uh) {
  int n = blockIdx.x*blockDim.x + threadIdx.x;
  if (n >= NPIX) return;
  float l[NCH];
  float m = -3.4e38f;
  #pragma unroll
  for (int c = 0; c < NCH; ++c) {
    l[c] = -U[(size_t)n*NCH+c];
    Uh[(size_t)n*USH+c] = __float2half(l[c]);
    m = fmaxf(m, l[c]);
  }
  float s = 0.f;
  #pragma unroll
  for (int c = 0; c < NCH; ++c) { l[c] = expf(l[c]-m); s += l[c]; }
  float r = 1.0f/s;
  #pragma unroll
  for (int c = 0; c < NCH; ++c) Qh[(size_t)n*QSH+c] = __float2half(l[c]*r);
  Qh[(size_t)n*QSH+NCH] = __float2half(0.f);   // ch21 read by half2 gather
}

template<bool FINAL, bool PACKED>
__global__ void slice_combine_softmax_kernel(
    const __half* __restrict__ Uh,
    const __half* __restrict__ vb, const __half* __restrict__ vsShift,
    const unsigned int* __restrict__ sl,
    const float* __restrict__ ws_b, const int* __restrict__ os_b,
    const float* __restrict__ ws_s, const int* __restrict__ os_s,
    float* __restrict__ QoutF, __half* __restrict__ QoutH) {
  int n = blockIdx.x*blockDim.x + threadIdx.x;
  if (n >= NPIX) return;
  float l[NCH];
  #pragma unroll
  for (int c = 0; c < NCH; ++c) l[c] = __half2float(Uh[(size_t)n*USH+c]);
  float acc[NCH2];
  #pragma unroll
  for (int c = 0; c < NCH2; ++c) acc[c] = 0.f;
  #pragma unroll
  for (int j = 0; j < 6; ++j) {
    float w; const __half* v;
    if (PACKED) {
      unsigned int e = sl[(size_t)j*NPIX + n];
      w = (float)(e & 4095u);
      v = vb + ((size_t)(e >> 12) << 5);
    } else {
      w = ws_b[n*6+j];
      v = vb + (size_t)(os_b[n*6+j]+1)*VSH;
    }
    #pragma unroll
    for (int c = 0; c < NCH2; ++c) acc[c] += w*__half2float(v[c]);
  }
  float rb = 10.0f/(acc[NCH] + 1e-12f);
  #pragma unroll
  for (int c = 0; c < NCH; ++c) l[c] += rb*acc[c];
  #pragma unroll
  for (int c = 0; c < NCH2; ++c) acc[c] = 0.f;
  #pragma unroll
  for (int j = 0; j < 3; ++j) {
    float w; const __half* v;
    if (PACKED) {
      unsigned int e = sl[(size_t)(6+j)*NPIX + n];
      w = (float)(e & 4095u);
      v = vsShift + ((size_t)(e >> 12) << 5);
    } else {
      w = ws_s[n*3+j];
      v = vsShift + (size_t)(os_s[n*3+j]+1)*VSH;
    }
    #pragma unroll
    for (int c = 0; c < NCH2; ++c) acc[c] += w*__half2float(v[c]);
  }
  float rs = 3.0f/(acc[NCH] + 1e-12f);
  #pragma unroll
  for (int c = 0; c < NCH; ++c) l[c] += rs*acc[c];
  float m = -3.4e38f;
  #pragma unroll
  for (int c = 0; c < NCH; ++c) m = fmaxf(m, l[c]);
  float s = 0.f;
  #pragma unroll
  for (int c = 0; c < NCH; ++c) { l[c] = expf(l[c]-m); s += l[c]; }
  float r = 1.0f/s;
  if (FINAL) {
    #pragma unroll
    for (int c = 0; c < NCH; ++c) QoutF[(size_t)n*NCH+c] = l[c]*r;
  } else {
    #pragma unroll
    for (int c = 0; c < NCH; ++c) QoutH[(size_t)n*QSH+c] = __float2half(l[c]*r);
    QoutH[(size_t)n*QSH+NCH] = __float2half(0.f);
  }
}

// ---------------- host ----------------

extern "C" void kernel_launch(void* const* d_in, const int* in_sizes, int n_in,
                              void* d_out, int out_size, void* d_ws, size_t ws_size,
                              hipStream_t stream) {
  const float* U    = (const float*)d_in[0];
  const float* ws_b = (const float*)d_in[1];
  const float* ws_s = (const float*)d_in[2];
  const int*   os_b = (const int*)d_in[3];
  const int*   os_s = (const int*)d_in[4];
  const int*   bn_b = (const int*)d_in[5];
  const int*   bn_s = (const int*)d_in[6];
  const int Mb = in_sizes[5] / 12;
  const int Ms = in_sizes[6] / 6;
  const int Mtot = Mb + Ms;
  const int nptot = NPIX*9;
  const bool packed = (Mtot + 1) < (1 << 20);

  char* wcur = (char*)d_ws;
  auto alloc = [&](size_t bytes) -> void* {
    void* p = (void*)wcur;
    wcur += (bytes + 63) & ~(size_t)63;
    return p;
  };
  __half* Qh     = (__half*)alloc((size_t)NPIX*QSH*2);
  __half* Uh     = (__half*)alloc((size_t)NPIX*USH*2);
  __half* vAb    = (__half*)alloc((size_t)(Mb+1)*VSH*2);
  __half* vBb    = (__half*)alloc((size_t)(Mb+1)*VSH*2);
  __half* vAs    = (__half*)alloc((size_t)(Ms+1)*VSH*2);
  __half* vBs    = (__half*)alloc((size_t)(Ms+1)*VSH*2);
  int*   start   = (int*)alloc((size_t)(Mtot+1)*4);
  int*   cur     = (int*)alloc((size_t)Mtot*4);
  unsigned int* pw = (unsigned int*)alloc((size_t)nptot*4);
  unsigned int* sl = (unsigned int*)alloc((size_t)nptot*4);
  int*   bsum    = (int*)alloc((size_t)(Mtot/256 + 3)*4);

  const int TB = 256;
  auto blocks = [](long long n){ return (int)((n + 255)/256); };
  const int nbM = blocks(Mtot);

  // ---- build: pack+count (one pass), scan, fill ----
  hipMemsetAsync(cur, 0, (size_t)Mtot*sizeof(int), stream);
  if (packed)
    pack_count_kernel<<<blocks(nptot), TB, 0, stream>>>(os_b, ws_b, os_s, ws_s,
                                                        sl, cur, nptot, Mb);
  else
    count_fused_kernel<<<blocks(nptot), TB, 0, stream>>>(os_b, os_s, cur, nptot, Mb);
  scan_block_kernel<<<nbM, 256, 0, stream>>>(cur, start, bsum, Mtot);
  scan_sums_kernel<<<1, 256, 0, stream>>>(bsum, nbM);
  scan_add_kernel<<<blocks(Mtot+1), TB, 0, stream>>>(start, bsum, Mtot, nbM);
  hipMemsetAsync(cur, 0, (size_t)Mtot*sizeof(int), stream);
  if (packed)
    fill_packed_kernel<<<blocks(nptot), TB, 0, stream>>>(sl, start, cur, pw, nptot);
  else
    fill_fused_kernel<<<blocks(nptot), TB, 0, stream>>>(os_b, ws_b, os_s, ws_s,
                                                        start, cur, pw, nptot, Mb);

  // ---- zero sentinel row 0 of value buffers ----
  hipMemsetAsync(vAb, 0, VSH*2, stream);
  hipMemsetAsync(vBb, 0, VSH*2, stream);
  hipMemsetAsync(vAs, 0, VSH*2, stream);
  hipMemsetAsync(vBs, 0, VSH*2, stream);

  softmax_init_kernel<<<blocks(NPIX), TB, 0, stream>>>(U, Qh, Uh);

  for (int it = 0; it < 5; ++it) {
    if (packed)
      gather_half2_kernel<<<blocks((long long)Mtot*64), TB, 0, stream>>>(
          Qh, start, pw, vAb, vAs, Mb, Mtot);
    else
      gather_wave_kernel<<<blocks((long long)Mtot*64), TB, 0, stream>>>(
          Qh, start, pw, vAb, vAs, Mb, Mtot);
    __half* ab = vAb; __half* bb = vBb;
    __half* as = vAs; __half* bs = vBs;
    for (int j = 0; j < 6; ++j) {
      int ms = (j < 3) ? Ms : 0;
      blurH_fused_kernel<<<blocks((long long)(Mb + ms)*11), TB, 0, stream>>>(
          ab, bb, bn_b + (size_t)j*Mb*2, Mb, as, bs, bn_s + (size_t)j*Ms*2, ms);
      { __half* t = ab; ab = bb; bb = t; }
      if (j < 3) { __half* t = as; as = bs; bs = t; }
    }
    // ab = final bilateral (vAb), as = final spatial (vBs)
    const __half* vsArg = packed ? (as - (size_t)Mb*VSH) : as;
    if (it == 4) {
      if (packed)
        slice_combine_softmax_kernel<true,true><<<blocks(NPIX), TB, 0, stream>>>(
            Uh, ab, vsArg, sl, ws_b, os_b, ws_s, os_s, (float*)d_out, (__half*)nullptr);
      else
        slice_combine_softmax_kernel<true,false><<<blocks(NPIX), TB, 0, stream>>>(
            Uh, ab, vsArg, sl, ws_b, os_b, ws_s, os_s, (float*)d_out, (__half*)nullptr);
    } else {
      if (packed)
        slice_combine_softmax_kernel<false,true><<<blocks(NPIX), TB, 0, stream>>>(
            Uh, ab, vsArg, sl, ws_b, os_b, ws_s, os_s, (float*)nullptr, Qh);
      else
        slice_combine_softmax_kernel<false,false><<<blocks(NPIX), TB, 0, stream>>>(
            Uh, ab, vsArg, sl, ws_b, os_b, ws_s, os_s, (float*)nullptr, Qh);
    }
  }
}